// Round 19
// baseline (56.642 us; speedup 1.0000x reference)
//
#include <hip/hip_runtime.h>
#include <hip/hip_fp16.h>
#include <math.h>

#define DIM     1024
#define NSTAGES 10
#define HALFD   512                   // angles per stage = DIM/2
#define TABN    (NSTAGES * HALFD)     // 5120 (cos,sin) half2 pairs = 20 KB

typedef float v4f __attribute__((ext_vector_type(4)));

// ---------------------------------------------------------------------------
// Cross-lane xor exchange, cheapest pipe per mask (all pieces proven):
//   m=1,2 : DPP quad_perm              (VALU)                [R7+]
//   m=4   : ds_swizzle BitMode xor     (DS)                  [R7+]
//   m=8   : DPP row_ror:8              (VALU, == xor8)       [R11/R18]
//   m=16,32: v_permlane{16,32}_swap    (VALU, pair trick)    [R10+]
// ---------------------------------------------------------------------------
__device__ __forceinline__ float xor1(float f) {   // quad_perm [1,0,3,2]
    return __builtin_bit_cast(float,
        __builtin_amdgcn_update_dpp(0, __builtin_bit_cast(int, f), 0xB1, 0xF, 0xF, true));
}
__device__ __forceinline__ float xor2(float f) {   // quad_perm [2,3,0,1]
    return __builtin_bit_cast(float,
        __builtin_amdgcn_update_dpp(0, __builtin_bit_cast(int, f), 0x4E, 0xF, 0xF, true));
}
__device__ __forceinline__ float xor4(float f) {   // proven DS path
    return __builtin_bit_cast(float,
        __builtin_amdgcn_ds_swizzle(__builtin_bit_cast(int, f), 0x101F));
}
__device__ __forceinline__ float xor8(float f) {   // row_ror:8 == xor8
    return __builtin_bit_cast(float,
        __builtin_amdgcn_update_dpp(0, __builtin_bit_cast(int, f), 0x128, 0xF, 0xF, true));
}

// half-swap primitives: exchange a's hi-group with b's lo-group (both regs)
__device__ __forceinline__ void pl16(float& a, float& b) {
    asm("v_permlane16_swap_b32 %0, %1" : "+v"(a), "+v"(b));
}
__device__ __forceinline__ void pl32(float& a, float& b) {
    asm("v_permlane32_swap_b32 %0, %1" : "+v"(a), "+v"(b));
}

// load 4 consecutive (cos,sin) half2 pairs as float4 C, float4 S
// -- ONE ds_read_b128 delivers both C and S (halves DS table traffic) [R14]
__device__ __forceinline__ void ldpair4(const __half2* __restrict__ t,
                                        float4& C, float4& S) {
    union { float4 f; __half2 h[4]; } u;
    u.f = *(const float4*)t;
    float2 a = __half22float2(u.h[0]);
    float2 b = __half22float2(u.h[1]);
    float2 c = __half22float2(u.h[2]);
    float2 d = __half22float2(u.h[3]);
    C = make_float4(a.x, b.x, c.x, d.x);
    S = make_float4(a.y, b.y, c.y, d.y);
}

// one cross-lane stage S (2..5) applied to a 2-row batch via value-exchange
#define XSTAGE(S, XORF)                                                    \
    {                                                                      \
        constexpr int m = 1 << ((S) - 2);                                  \
        const __half2* tS = tabL + (S) * HALFD;                            \
        const int l0 = lane & ~m;                                          \
        const float sgn = (lane & m) ? -1.0f : 1.0f;                       \
        _Pragma("unroll")                                                  \
        for (int c = 0; c < 4; ++c) {                                      \
            const int p0 = (((c << (7 - (S))) + (l0 >> ((S) - 1))) << (S)) \
                         + 4 * (l0 & (m - 1));                             \
            float4 C, Sv;                                                  \
            ldpair4(tS + p0, C, Sv);                                       \
            Sv.x *= sgn; Sv.y *= sgn; Sv.z *= sgn; Sv.w *= sgn;            \
            _Pragma("unroll")                                              \
            for (int r = 0; r < 2; ++r) {                                  \
                float4 u = v[r][c];                                        \
                float tx = XORF(u.x), ty = XORF(u.y);                      \
                float tz = XORF(u.z), tw = XORF(u.w);                      \
                v[r][c].x = C.x * u.x + Sv.x * tx;                         \
                v[r][c].y = C.y * u.y + Sv.y * ty;                         \
                v[r][c].z = C.z * u.z + Sv.z * tz;                         \
                v[r][c].w = C.w * u.w + Sv.w * tw;                         \
            }                                                              \
        }                                                                  \
    }

// permlane pair-trick on two SAME-ROW components A,B (rows independent)
#define PLPAIR(A, B, Cv, Svv, PLFN)                                        \
    {                                                                      \
        float a_ = (A), b_ = (B);                                          \
        PLFN(a_, b_);                                                      \
        float an_ = Cv * a_ + Svv * b_;   /* left'  */                     \
        float bn_ = Cv * b_ - Svv * a_;   /* right' */                     \
        PLFN(an_, bn_);                                                    \
        (A) = an_; (B) = bn_;                                              \
    }

// stage S in {6,7}: lo lanes compute A's pair (C.x/S.x, C.z/S.z); hi lanes B's
#define XSTAGE_PL(S, PLFN, SELBIT)                                         \
    {                                                                      \
        constexpr int m = 1 << ((S) - 2);                                  \
        const __half2* tS = tabL + (S) * HALFD;                            \
        const int l0 = lane & ~m;                                          \
        const bool hi = (lane & (SELBIT)) != 0;                            \
        _Pragma("unroll")                                                  \
        for (int c = 0; c < 4; ++c) {                                      \
            const int p0 = (((c << (7 - (S))) + (l0 >> ((S) - 1))) << (S)) \
                         + 4 * (l0 & (m - 1));                             \
            float4 C, Sv;                                                  \
            ldpair4(tS + p0, C, Sv);                                       \
            float cxy = hi ? C.y : C.x,  sxy = hi ? Sv.y : Sv.x;           \
            float czw = hi ? C.w : C.z,  szw = hi ? Sv.w : Sv.z;           \
            _Pragma("unroll")                                              \
            for (int r = 0; r < 2; ++r) {                                  \
                PLPAIR(v[r][c].x, v[r][c].y, cxy, sxy, PLFN)               \
                PLPAIR(v[r][c].z, v[r][c].w, czw, szw, PLFN)               \
            }                                                              \
        }                                                                  \
    }

// ---------------------------------------------------------------------------
// Process one 2-row batch through all 10 stages (proven no-spill working set)
// ---------------------------------------------------------------------------
__device__ __forceinline__ void processBatch(float4 (&v)[2][4],
                                             const __half2* __restrict__ tabL,
                                             int lane)
{
    // ---- stages 0,1: intra-float4. pairs at p, p+1 -----------------------
    #pragma unroll
    for (int s01 = 0; s01 < 2; ++s01) {
        const __half2* t0 = tabL + s01 * HALFD;
        #pragma unroll
        for (int c = 0; c < 4; ++c) {
            const int p = 128 * c + 2 * lane;
            float2 q0 = __half22float2(t0[p]);
            float2 q1 = __half22float2(t0[p + 1]);
            float2 cc = make_float2(q0.x, q1.x);
            float2 ss = make_float2(q0.y, q1.y);
            #pragma unroll
            for (int r = 0; r < 2; ++r) {
                float4 u = v[r][c];
                if (s01 == 0) {
                    v[r][c].x = cc.x * u.x + ss.x * u.y;
                    v[r][c].y = cc.x * u.y - ss.x * u.x;
                    v[r][c].z = cc.y * u.z + ss.y * u.w;
                    v[r][c].w = cc.y * u.w - ss.y * u.z;
                } else {
                    v[r][c].x = cc.x * u.x + ss.x * u.z;
                    v[r][c].z = cc.x * u.z - ss.x * u.x;
                    v[r][c].y = cc.y * u.y + ss.y * u.w;
                    v[r][c].w = cc.y * u.w - ss.y * u.y;
                }
            }
        }
    }

    // ---- stages 2..7: cross-lane exchanges -------------------------------
    XSTAGE(2, xor1)
    XSTAGE(3, xor2)
    XSTAGE(4, xor4)
    XSTAGE(5, xor8)
    XSTAGE_PL(6, pl16, 16)
    XSTAGE_PL(7, pl32, 32)

    // ---- stage 8: pairs (c0,c1),(c2,c3); p = 256*g + 4*lane --------------
    {
        const __half2* tS = tabL + 8 * HALFD;
        #pragma unroll
        for (int g = 0; g < 2; ++g) {
            float4 C, S;
            ldpair4(tS + 256 * g + 4 * lane, C, S);
            #pragma unroll
            for (int r = 0; r < 2; ++r) {
                float4 L = v[r][2 * g], Rr = v[r][2 * g + 1];
                v[r][2 * g].x     = C.x * L.x + S.x * Rr.x;
                v[r][2 * g].y     = C.y * L.y + S.y * Rr.y;
                v[r][2 * g].z     = C.z * L.z + S.z * Rr.z;
                v[r][2 * g].w     = C.w * L.w + S.w * Rr.w;
                v[r][2 * g + 1].x = C.x * Rr.x - S.x * L.x;
                v[r][2 * g + 1].y = C.y * Rr.y - S.y * L.y;
                v[r][2 * g + 1].z = C.z * Rr.z - S.z * L.z;
                v[r][2 * g + 1].w = C.w * Rr.w - S.w * L.w;
            }
        }
    }

    // ---- stage 9: pairs (c0,c2),(c1,c3) ----------------------------------
    {
        const __half2* tS = tabL + 9 * HALFD;
        #pragma unroll
        for (int g = 0; g < 2; ++g) {
            float4 C, S;
            ldpair4(tS + 256 * g + 4 * lane, C, S);
            #pragma unroll
            for (int r = 0; r < 2; ++r) {
                float4 L = v[r][g], Rr = v[r][g + 2];
                v[r][g].x     = C.x * L.x + S.x * Rr.x;
                v[r][g].y     = C.y * L.y + S.y * Rr.y;
                v[r][g].z     = C.z * L.z + S.z * Rr.z;
                v[r][g].w     = C.w * L.w + S.w * Rr.w;
                v[r][g + 2].x = C.x * Rr.x - S.x * L.x;
                v[r][g + 2].y = C.y * Rr.y - S.y * L.y;
                v[r][g + 2].z = C.z * Rr.z - S.z * L.z;
                v[r][g + 2].w = C.w * Rr.w - S.w * L.w;
            }
        }
    }
}

__device__ __forceinline__ void storeRowNT(float4* __restrict__ op, const float4& a) {
    v4f t = { a.x, a.y, a.z, a.w };
    __builtin_nontemporal_store(t, (v4f*)op);
}

// ---------------------------------------------------------------------------
// Main (single kernel; R18 champion skeleton + occupancy unlock):
//  - fp16 (cos,sin)-pair LDS table, 20 KB  [accuracy proven R14: 0.031]
//  - __launch_bounds__(256,5): VGPR cap 102 [no-spill proven R13]
//    -> 5 waves/SIMD, 20 waves/CU (+25% TLP vs all prior rounds)
//  - in-kernel table gen via HW v_sin/v_cos; batch-0 loads before it,
//    batch-1 loads right after the barrier; NT stores
// ---------------------------------------------------------------------------
__global__ __launch_bounds__(256, 5) void bf_main(
    const float* __restrict__ x,
    const float* __restrict__ ang,
    float* __restrict__ out)
{
    __shared__ __align__(16) __half2 tabL[TABN];    // 20 KB
    const int tid  = threadIdx.x;
    const int lane = tid & 63;
    const int gwid = blockIdx.x * 4 + (tid >> 6);   // global wave id, 4 rows each

    const float4* xp = (const float4*)x   + (size_t)gwid * 4 * (DIM / 4) + lane;
    float4*       op = (float4*)      out + (size_t)gwid * 4 * (DIM / 4) + lane;

    // ---- batch 0 payload loads FIRST (hidden under table generation) -----
    float4 v0[2][4];
    #pragma unroll
    for (int r = 0; r < 2; ++r)
        #pragma unroll
        for (int c = 0; c < 4; ++c)
            v0[r][c] = xp[r * 256 + c * 64];

    // ---- in-kernel table gen: HW v_sin/v_cos -> fp16 pairs ---------------
    {
        const float2* a2 = (const float2*)ang;
        const float r2pi = 0.15915494309189535f;   // 1/(2*pi)
        #pragma unroll 1
        for (int k = 0; k < TABN / 2 / 256; ++k) {   // 10 iterations
            const int idx = k * 256 + tid;           // angle-pair index
            float2 a = a2[idx];
            float fa = a.x * r2pi; fa -= floorf(fa);
            float fb = a.y * r2pi; fb -= floorf(fb);
            float ca = __builtin_amdgcn_cosf(fa);
            float sa = __builtin_amdgcn_sinf(fa);
            float cb = __builtin_amdgcn_cosf(fb);
            float sb = __builtin_amdgcn_sinf(fb);
            tabL[2 * idx]     = __halves2half2(__float2half_rn(ca), __float2half_rn(sa));
            tabL[2 * idx + 1] = __halves2half2(__float2half_rn(cb), __float2half_rn(sb));
        }
    }

    __syncthreads();

    // ---- batch 1 loads issue NOW: latency hides under batch-0 compute ----
    float4 v1[2][4];
    #pragma unroll
    for (int r = 0; r < 2; ++r)
        #pragma unroll
        for (int c = 0; c < 4; ++c)
            v1[r][c] = xp[(2 + r) * 256 + c * 64];

    {
        float4 (&v)[2][4] = v0;
        processBatch(v, tabL, lane);
    }
    #pragma unroll
    for (int r = 0; r < 2; ++r)
        #pragma unroll
        for (int c = 0; c < 4; ++c)
            storeRowNT(op + r * 256 + c * 64, v0[r][c]);

    asm volatile("" ::: "memory");   // fence: no cross-batch hoist/CSE

    {
        float4 (&v)[2][4] = v1;
        processBatch(v, tabL, lane);
    }
    #pragma unroll
    for (int r = 0; r < 2; ++r)
        #pragma unroll
        for (int c = 0; c < 4; ++c)
            storeRowNT(op + (2 + r) * 256 + c * 64, v1[r][c]);
}

extern "C" void kernel_launch(void* const* d_in, const int* in_sizes, int n_in,
                              void* d_out, int out_size, void* d_ws, size_t ws_size,
                              hipStream_t stream) {
    const float* x   = (const float*)d_in[0];
    const float* ang = (const float*)d_in[1];
    float* out = (float*)d_out;

    const int nrows = out_size / DIM;          // 16384
    // 4 waves/block x 4 rows/wave = 16 rows/block -> 1024 blocks;
    // 20 KB LDS + 102-VGPR cap -> 5 blocks/CU capacity, grid needs 4/CU
    // -> whole grid resident, 20 waves/CU.
    const int nblocks = nrows / 16;

    bf_main<<<nblocks, 256, 0, stream>>>(x, ang, out);
}

// Round 20
// 32.896 us; speedup vs baseline: 1.7218x; 1.7218x over previous
//
#include <hip/hip_runtime.h>
#include <hip/hip_fp16.h>
#include <math.h>

#define DIM     1024
#define NSTAGES 10
#define HALFD   512                   // angles per stage = DIM/2
#define TABN    (NSTAGES * HALFD)     // 5120 (cos,sin) half2 pairs = 20 KB

typedef float v4f __attribute__((ext_vector_type(4)));

// ---------------------------------------------------------------------------
// Cross-lane xor exchange, cheapest pipe per mask (all pieces proven):
//   m=1,2 : DPP quad_perm              (VALU)                [R7+]
//   m=4   : ds_swizzle BitMode xor     (DS)                  [R7+]
//   m=8   : DPP row_ror:8              (VALU, == xor8)       [R11/R18]
//   m=16,32: v_permlane{16,32}_swap    (VALU, pair trick)    [R10+]
// ---------------------------------------------------------------------------
__device__ __forceinline__ float xor1(float f) {   // quad_perm [1,0,3,2]
    return __builtin_bit_cast(float,
        __builtin_amdgcn_update_dpp(0, __builtin_bit_cast(int, f), 0xB1, 0xF, 0xF, true));
}
__device__ __forceinline__ float xor2(float f) {   // quad_perm [2,3,0,1]
    return __builtin_bit_cast(float,
        __builtin_amdgcn_update_dpp(0, __builtin_bit_cast(int, f), 0x4E, 0xF, 0xF, true));
}
__device__ __forceinline__ float xor4(float f) {   // proven DS path
    return __builtin_bit_cast(float,
        __builtin_amdgcn_ds_swizzle(__builtin_bit_cast(int, f), 0x101F));
}
__device__ __forceinline__ float xor8(float f) {   // row_ror:8 == xor8
    return __builtin_bit_cast(float,
        __builtin_amdgcn_update_dpp(0, __builtin_bit_cast(int, f), 0x128, 0xF, 0xF, true));
}

// half-swap primitives: exchange a's hi-group with b's lo-group (both regs)
__device__ __forceinline__ void pl16(float& a, float& b) {
    asm("v_permlane16_swap_b32 %0, %1" : "+v"(a), "+v"(b));
}
__device__ __forceinline__ void pl32(float& a, float& b) {
    asm("v_permlane32_swap_b32 %0, %1" : "+v"(a), "+v"(b));
}

// load 4 consecutive (cos,sin) half2 pairs as float4 C, float4 S
// -- ONE ds_read_b128 delivers both C and S [R14/R19-proven correct]
__device__ __forceinline__ void ldpair4(const __half2* __restrict__ t,
                                        float4& C, float4& S) {
    union { float4 f; __half2 h[4]; } u;
    u.f = *(const float4*)t;
    float2 a = __half22float2(u.h[0]);
    float2 b = __half22float2(u.h[1]);
    float2 c = __half22float2(u.h[2]);
    float2 d = __half22float2(u.h[3]);
    C = make_float4(a.x, b.x, c.x, d.x);
    S = make_float4(a.y, b.y, c.y, d.y);
}

// one cross-lane stage S (2..5) applied to ONE row (v = float4[4])
#define XSTAGE(S, XORF)                                                    \
    {                                                                      \
        constexpr int m = 1 << ((S) - 2);                                  \
        const __half2* tS = tabL + (S) * HALFD;                            \
        const int l0 = lane & ~m;                                          \
        const float sgn = (lane & m) ? -1.0f : 1.0f;                       \
        _Pragma("unroll")                                                  \
        for (int c = 0; c < 4; ++c) {                                      \
            const int p0 = (((c << (7 - (S))) + (l0 >> ((S) - 1))) << (S)) \
                         + 4 * (l0 & (m - 1));                             \
            float4 C, Sv;                                                  \
            ldpair4(tS + p0, C, Sv);                                       \
            Sv.x *= sgn; Sv.y *= sgn; Sv.z *= sgn; Sv.w *= sgn;            \
            float4 u = v[c];                                               \
            float tx = XORF(u.x), ty = XORF(u.y);                          \
            float tz = XORF(u.z), tw = XORF(u.w);                          \
            v[c].x = C.x * u.x + Sv.x * tx;                                \
            v[c].y = C.y * u.y + Sv.y * ty;                                \
            v[c].z = C.z * u.z + Sv.z * tz;                                \
            v[c].w = C.w * u.w + Sv.w * tw;                                \
        }                                                                  \
    }

// permlane pair-trick on two SAME-ROW components A,B [R10-proven]
#define PLPAIR(A, B, Cv, Svv, PLFN)                                        \
    {                                                                      \
        float a_ = (A), b_ = (B);                                          \
        PLFN(a_, b_);                                                      \
        float an_ = Cv * a_ + Svv * b_;   /* left'  */                     \
        float bn_ = Cv * b_ - Svv * a_;   /* right' */                     \
        PLFN(an_, bn_);                                                    \
        (A) = an_; (B) = bn_;                                              \
    }

// stage S in {6,7}: lo lanes compute A's pair (C.x/S.x, C.z/S.z); hi lanes B's
#define XSTAGE_PL(S, PLFN, SELBIT)                                         \
    {                                                                      \
        constexpr int m = 1 << ((S) - 2);                                  \
        const __half2* tS = tabL + (S) * HALFD;                            \
        const int l0 = lane & ~m;                                          \
        const bool hi = (lane & (SELBIT)) != 0;                            \
        _Pragma("unroll")                                                  \
        for (int c = 0; c < 4; ++c) {                                      \
            const int p0 = (((c << (7 - (S))) + (l0 >> ((S) - 1))) << (S)) \
                         + 4 * (l0 & (m - 1));                             \
            float4 C, Sv;                                                  \
            ldpair4(tS + p0, C, Sv);                                       \
            float cxy = hi ? C.y : C.x,  sxy = hi ? Sv.y : Sv.x;           \
            float czw = hi ? C.w : C.z,  szw = hi ? Sv.w : Sv.z;           \
            PLPAIR(v[c].x, v[c].y, cxy, sxy, PLFN)                         \
            PLPAIR(v[c].z, v[c].w, czw, szw, PLFN)                         \
        }                                                                  \
    }

// ---------------------------------------------------------------------------
// Process ONE row through all 10 stages. Working set: 16 data VGPRs + ~16
// table/temp — natural allocation well under 85 (6+ waves/SIMD, no cap).
// ---------------------------------------------------------------------------
__device__ __forceinline__ void processRow(float4 (&v)[4],
                                           const __half2* __restrict__ tabL,
                                           int lane)
{
    // ---- stages 0,1: intra-float4. pairs at p, p+1 -----------------------
    #pragma unroll
    for (int s01 = 0; s01 < 2; ++s01) {
        const __half2* t0 = tabL + s01 * HALFD;
        #pragma unroll
        for (int c = 0; c < 4; ++c) {
            const int p = 128 * c + 2 * lane;
            float2 q0 = __half22float2(t0[p]);
            float2 q1 = __half22float2(t0[p + 1]);
            float4 u = v[c];
            if (s01 == 0) {
                v[c].x = q0.x * u.x + q0.y * u.y;
                v[c].y = q0.x * u.y - q0.y * u.x;
                v[c].z = q1.x * u.z + q1.y * u.w;
                v[c].w = q1.x * u.w - q1.y * u.z;
            } else {
                v[c].x = q0.x * u.x + q0.y * u.z;
                v[c].z = q0.x * u.z - q0.y * u.x;
                v[c].y = q1.x * u.y + q1.y * u.w;
                v[c].w = q1.x * u.w - q1.y * u.y;
            }
        }
    }

    // ---- stages 2..7: cross-lane exchanges -------------------------------
    XSTAGE(2, xor1)
    XSTAGE(3, xor2)
    XSTAGE(4, xor4)
    XSTAGE(5, xor8)
    XSTAGE_PL(6, pl16, 16)
    XSTAGE_PL(7, pl32, 32)

    // ---- stage 8: pairs (c0,c1),(c2,c3); p = 256*g + 4*lane --------------
    {
        const __half2* tS = tabL + 8 * HALFD;
        #pragma unroll
        for (int g = 0; g < 2; ++g) {
            float4 C, S;
            ldpair4(tS + 256 * g + 4 * lane, C, S);
            float4 L = v[2 * g], Rr = v[2 * g + 1];
            v[2 * g].x     = C.x * L.x + S.x * Rr.x;
            v[2 * g].y     = C.y * L.y + S.y * Rr.y;
            v[2 * g].z     = C.z * L.z + S.z * Rr.z;
            v[2 * g].w     = C.w * L.w + S.w * Rr.w;
            v[2 * g + 1].x = C.x * Rr.x - S.x * L.x;
            v[2 * g + 1].y = C.y * Rr.y - S.y * L.y;
            v[2 * g + 1].z = C.z * Rr.z - S.z * L.z;
            v[2 * g + 1].w = C.w * Rr.w - S.w * L.w;
        }
    }

    // ---- stage 9: pairs (c0,c2),(c1,c3) ----------------------------------
    {
        const __half2* tS = tabL + 9 * HALFD;
        #pragma unroll
        for (int g = 0; g < 2; ++g) {
            float4 C, S;
            ldpair4(tS + 256 * g + 4 * lane, C, S);
            float4 L = v[g], Rr = v[g + 2];
            v[g].x     = C.x * L.x + S.x * Rr.x;
            v[g].y     = C.y * L.y + S.y * Rr.y;
            v[g].z     = C.z * L.z + S.z * Rr.z;
            v[g].w     = C.w * L.w + S.w * Rr.w;
            v[g + 2].x = C.x * Rr.x - S.x * L.x;
            v[g + 2].y = C.y * Rr.y - S.y * L.y;
            v[g + 2].z = C.z * Rr.z - S.z * L.z;
            v[g + 2].w = C.w * Rr.w - S.w * L.w;
        }
    }
}

__device__ __forceinline__ void loadRow(float4 (&v)[4],
                                        const float4* __restrict__ xp, int row) {
    #pragma unroll
    for (int c = 0; c < 4; ++c)
        v[c] = xp[row * 256 + c * 64];
}

__device__ __forceinline__ void storeRowNT(float4* __restrict__ op, int row,
                                           const float4 (&v)[4]) {
    #pragma unroll
    for (int c = 0; c < 4; ++c) {
        v4f t = { v[c].x, v[c].y, v[c].z, v[c].w };
        __builtin_nontemporal_store(t, (v4f*)(op + row * 256 + c * 64));
    }
}

// ---------------------------------------------------------------------------
// Main: 1024 blocks x 4 waves x 4 rows, processed as FOUR fenced 1-row
// batches in a vA/vB ping-pong (static indexing; fences block cross-batch
// table CSE). fp16 pair table = 20 KB LDS -> 8 blocks/CU capacity; natural
// VGPR ~60-75 -> 6-7 waves/SIMD. NO launch_bounds cap (caps spill: R4/R7/R19).
// Occupancy 16 -> 24-28 waves/CU: the clean latency-hiding test.
// ---------------------------------------------------------------------------
__global__ __launch_bounds__(256) void bf_main(
    const float* __restrict__ x,
    const float* __restrict__ ang,
    float* __restrict__ out)
{
    __shared__ __align__(16) __half2 tabL[TABN];    // 20 KB
    const int tid  = threadIdx.x;
    const int lane = tid & 63;
    const int gwid = blockIdx.x * 4 + (tid >> 6);   // global wave id, 4 rows each

    const float4* xp = (const float4*)x   + (size_t)gwid * 4 * (DIM / 4) + lane;
    float4*       op = (float4*)      out + (size_t)gwid * 4 * (DIM / 4) + lane;

    // ---- row 0 loads FIRST (hidden under table generation) ---------------
    float4 vA[4], vB[4];
    loadRow(vA, xp, 0);

    // ---- in-kernel table gen: HW v_sin/v_cos -> fp16 pairs ---------------
    {
        const float2* a2 = (const float2*)ang;
        const float r2pi = 0.15915494309189535f;   // 1/(2*pi)
        #pragma unroll 1
        for (int k = 0; k < TABN / 2 / 256; ++k) {   // 10 iterations
            const int idx = k * 256 + tid;           // angle-pair index
            float2 a = a2[idx];
            float fa = a.x * r2pi; fa -= floorf(fa);
            float fb = a.y * r2pi; fb -= floorf(fb);
            float ca = __builtin_amdgcn_cosf(fa);
            float sa = __builtin_amdgcn_sinf(fa);
            float cb = __builtin_amdgcn_cosf(fb);
            float sb = __builtin_amdgcn_sinf(fb);
            tabL[2 * idx]     = __halves2half2(__float2half_rn(ca), __float2half_rn(sa));
            tabL[2 * idx + 1] = __halves2half2(__float2half_rn(cb), __float2half_rn(sb));
        }
    }

    __syncthreads();

    // ---- 4-deep ping-pong: load(i+1) in flight while process(i) ----------
    loadRow(vB, xp, 1);
    processRow(vA, tabL, lane);
    storeRowNT(op, 0, vA);
    asm volatile("" ::: "memory");

    loadRow(vA, xp, 2);
    processRow(vB, tabL, lane);
    storeRowNT(op, 1, vB);
    asm volatile("" ::: "memory");

    loadRow(vB, xp, 3);
    processRow(vA, tabL, lane);
    storeRowNT(op, 2, vA);
    asm volatile("" ::: "memory");

    processRow(vB, tabL, lane);
    storeRowNT(op, 3, vB);
}

extern "C" void kernel_launch(void* const* d_in, const int* in_sizes, int n_in,
                              void* d_out, int out_size, void* d_ws, size_t ws_size,
                              hipStream_t stream) {
    const float* x   = (const float*)d_in[0];
    const float* ang = (const float*)d_in[1];
    float* out = (float*)d_out;

    const int nrows = out_size / DIM;          // 16384
    // 4 waves/block x 4 rows/wave = 16 rows/block -> 1024 blocks.
    const int nblocks = nrows / 16;

    bf_main<<<nblocks, 256, 0, stream>>>(x, ang, out);
}

// Round 22
// 28.111 us; speedup vs baseline: 2.0150x; 1.1702x over previous
//
#include <hip/hip_runtime.h>
#include <math.h>

#define DIM     1024
#define NSTAGES 10
#define HALFD   512                   // angles per stage = DIM/2
#define TABN    (NSTAGES * HALFD)     // 5120 floats per table

typedef float v4f __attribute__((ext_vector_type(4)));

// ---------------------------------------------------------------------------
// Cross-lane xor exchange, cheapest pipe per mask (all pieces proven):
//   m=1,2 : DPP quad_perm              (VALU)                [R7+]
//   m=4   : ds_swizzle BitMode xor     (DS)                  [R7+]
//   m=8   : DPP row_ror:8              (VALU, == xor8)       [R11/R18]
//   m=16,32: v_permlane{16,32}_swap    (VALU, pair trick)    [R10+]
// R17 lesson: bank-masked DPP xor4 was wrong (direction semantics).
// R21 lesson: fp16 pair-table + this exchange mix is schedule-dependently
// broken (passed capped/R19, failed uncapped/R21) — fp32 tables only.
// ---------------------------------------------------------------------------
__device__ __forceinline__ float xor1(float f) {   // quad_perm [1,0,3,2]
    return __builtin_bit_cast(float,
        __builtin_amdgcn_update_dpp(0, __builtin_bit_cast(int, f), 0xB1, 0xF, 0xF, true));
}
__device__ __forceinline__ float xor2(float f) {   // quad_perm [2,3,0,1]
    return __builtin_bit_cast(float,
        __builtin_amdgcn_update_dpp(0, __builtin_bit_cast(int, f), 0x4E, 0xF, 0xF, true));
}
__device__ __forceinline__ float xor4(float f) {   // proven DS path
    return __builtin_bit_cast(float,
        __builtin_amdgcn_ds_swizzle(__builtin_bit_cast(int, f), 0x101F));
}
__device__ __forceinline__ float xor8(float f) {   // row_ror:8 == xor8
    return __builtin_bit_cast(float,
        __builtin_amdgcn_update_dpp(0, __builtin_bit_cast(int, f), 0x128, 0xF, 0xF, true));
}

// half-swap primitives: exchange a's hi-group with b's lo-group (both regs)
__device__ __forceinline__ void pl16(float& a, float& b) {
    asm("v_permlane16_swap_b32 %0, %1" : "+v"(a), "+v"(b));
}
__device__ __forceinline__ void pl32(float& a, float& b) {
    asm("v_permlane32_swap_b32 %0, %1" : "+v"(a), "+v"(b));
}

// one cross-lane stage S (2..5) applied to a 2-row batch via value-exchange
#define XSTAGE(S, XORF)                                                    \
    {                                                                      \
        constexpr int m = 1 << ((S) - 2);                                  \
        const float* cT = cosT + (S) * HALFD;                              \
        const float* sT = sinT + (S) * HALFD;                              \
        const int l0 = lane & ~m;                                          \
        const float sgn = (lane & m) ? -1.0f : 1.0f;                       \
        _Pragma("unroll")                                                  \
        for (int c = 0; c < 4; ++c) {                                      \
            const int p0 = (((c << (7 - (S))) + (l0 >> ((S) - 1))) << (S)) \
                         + 4 * (l0 & (m - 1));                             \
            float4 C = *(const float4*)&cT[p0];                            \
            float4 Sv = *(const float4*)&sT[p0];                           \
            Sv.x *= sgn; Sv.y *= sgn; Sv.z *= sgn; Sv.w *= sgn;            \
            _Pragma("unroll")                                              \
            for (int r = 0; r < 2; ++r) {                                  \
                float4 u = v[r][c];                                        \
                float tx = XORF(u.x), ty = XORF(u.y);                      \
                float tz = XORF(u.z), tw = XORF(u.w);                      \
                v[r][c].x = C.x * u.x + Sv.x * tx;                         \
                v[r][c].y = C.y * u.y + Sv.y * ty;                         \
                v[r][c].z = C.z * u.z + Sv.z * tz;                         \
                v[r][c].w = C.w * u.w + Sv.w * tw;                         \
            }                                                              \
        }                                                                  \
    }

// permlane pair-trick on two SAME-ROW components A,B (rows independent)
#define PLPAIR(A, B, Cv, Svv, PLFN)                                        \
    {                                                                      \
        float a_ = (A), b_ = (B);                                          \
        PLFN(a_, b_);                                                      \
        float an_ = Cv * a_ + Svv * b_;   /* left'  */                     \
        float bn_ = Cv * b_ - Svv * a_;   /* right' */                     \
        PLFN(an_, bn_);                                                    \
        (A) = an_; (B) = bn_;                                              \
    }

// stage S in {6,7}: lo lanes compute A's pair (C.x/S.x, C.z/S.z); hi lanes B's
#define XSTAGE_PL(S, PLFN, SELBIT)                                         \
    {                                                                      \
        constexpr int m = 1 << ((S) - 2);                                  \
        const float* cT = cosT + (S) * HALFD;                              \
        const float* sT = sinT + (S) * HALFD;                              \
        const int l0 = lane & ~m;                                          \
        const bool hi = (lane & (SELBIT)) != 0;                            \
        _Pragma("unroll")                                                  \
        for (int c = 0; c < 4; ++c) {                                      \
            const int p0 = (((c << (7 - (S))) + (l0 >> ((S) - 1))) << (S)) \
                         + 4 * (l0 & (m - 1));                             \
            float4 C = *(const float4*)&cT[p0];                            \
            float4 Sv = *(const float4*)&sT[p0];                           \
            float cxy = hi ? C.y : C.x,  sxy = hi ? Sv.y : Sv.x;           \
            float czw = hi ? C.w : C.z,  szw = hi ? Sv.w : Sv.z;           \
            _Pragma("unroll")                                              \
            for (int r = 0; r < 2; ++r) {                                  \
                PLPAIR(v[r][c].x, v[r][c].y, cxy, sxy, PLFN)               \
                PLPAIR(v[r][c].z, v[r][c].w, czw, szw, PLFN)               \
            }                                                              \
        }                                                                  \
    }

// ---------------------------------------------------------------------------
// Process one 2-row batch through all 10 stages (proven no-spill working set)
// ---------------------------------------------------------------------------
__device__ __forceinline__ void processBatch(float4 (&v)[2][4],
                                             const float* __restrict__ cosT,
                                             const float* __restrict__ sinT,
                                             int lane)
{
    // ---- stages 0,1: intra-float4. p = 128c + 2*lane + {0,1} -------------
    #pragma unroll
    for (int s01 = 0; s01 < 2; ++s01) {
        const float* cT = cosT + s01 * HALFD;
        const float* sT = sinT + s01 * HALFD;
        #pragma unroll
        for (int c = 0; c < 4; ++c) {
            const int p = 128 * c + 2 * lane;
            float2 cc = *(const float2*)&cT[p];
            float2 ss = *(const float2*)&sT[p];
            #pragma unroll
            for (int r = 0; r < 2; ++r) {
                float4 u = v[r][c];
                if (s01 == 0) {
                    v[r][c].x = cc.x * u.x + ss.x * u.y;
                    v[r][c].y = cc.x * u.y - ss.x * u.x;
                    v[r][c].z = cc.y * u.z + ss.y * u.w;
                    v[r][c].w = cc.y * u.w - ss.y * u.z;
                } else {
                    v[r][c].x = cc.x * u.x + ss.x * u.z;
                    v[r][c].z = cc.x * u.z - ss.x * u.x;
                    v[r][c].y = cc.y * u.y + ss.y * u.w;
                    v[r][c].w = cc.y * u.w - ss.y * u.y;
                }
            }
        }
    }

    // ---- stages 2..7: cross-lane exchanges -------------------------------
    XSTAGE(2, xor1)
    XSTAGE(3, xor2)
    XSTAGE(4, xor4)
    XSTAGE(5, xor8)
    XSTAGE_PL(6, pl16, 16)
    XSTAGE_PL(7, pl32, 32)

    // ---- stage 8: pairs (c0,c1),(c2,c3); p = 256*g + 4*lane + d ----------
    {
        const float* cT = cosT + 8 * HALFD;
        const float* sT = sinT + 8 * HALFD;
        #pragma unroll
        for (int g = 0; g < 2; ++g) {
            const int p0 = 256 * g + 4 * lane;
            float4 C = *(const float4*)&cT[p0];
            float4 S = *(const float4*)&sT[p0];
            #pragma unroll
            for (int r = 0; r < 2; ++r) {
                float4 L = v[r][2 * g], Rr = v[r][2 * g + 1];
                v[r][2 * g].x     = C.x * L.x + S.x * Rr.x;
                v[r][2 * g].y     = C.y * L.y + S.y * Rr.y;
                v[r][2 * g].z     = C.z * L.z + S.z * Rr.z;
                v[r][2 * g].w     = C.w * L.w + S.w * Rr.w;
                v[r][2 * g + 1].x = C.x * Rr.x - S.x * L.x;
                v[r][2 * g + 1].y = C.y * Rr.y - S.y * L.y;
                v[r][2 * g + 1].z = C.z * Rr.z - S.z * L.z;
                v[r][2 * g + 1].w = C.w * Rr.w - S.w * L.w;
            }
        }
    }

    // ---- stage 9: pairs (c0,c2),(c1,c3) ----------------------------------
    {
        const float* cT = cosT + 9 * HALFD;
        const float* sT = sinT + 9 * HALFD;
        #pragma unroll
        for (int g = 0; g < 2; ++g) {
            const int p0 = 256 * g + 4 * lane;
            float4 C = *(const float4*)&cT[p0];
            float4 S = *(const float4*)&sT[p0];
            #pragma unroll
            for (int r = 0; r < 2; ++r) {
                float4 L = v[r][g], Rr = v[r][g + 2];
                v[r][g].x     = C.x * L.x + S.x * Rr.x;
                v[r][g].y     = C.y * L.y + S.y * Rr.y;
                v[r][g].z     = C.z * L.z + S.z * Rr.z;
                v[r][g].w     = C.w * L.w + S.w * Rr.w;
                v[r][g + 2].x = C.x * Rr.x - S.x * L.x;
                v[r][g + 2].y = C.y * Rr.y - S.y * L.y;
                v[r][g + 2].z = C.z * Rr.z - S.z * L.z;
                v[r][g + 2].w = C.w * Rr.w - S.w * L.w;
            }
        }
    }
}

__device__ __forceinline__ void storeRowNT(float4* __restrict__ op, const float4& a) {
    v4f t = { a.x, a.y, a.z, a.w };
    __builtin_nontemporal_store(t, (v4f*)op);
}

// ---------------------------------------------------------------------------
// Main (single kernel; the R18 champion, restored verbatim):
//  - in-kernel table gen via HW v_sin/v_cos (no prep dispatch)    [R15 +1.2us]
//  - fp32 split cos/sin LDS tables, 40 KB                          [R1-proven]
//  - batch-0 loads before table gen; batch-1 loads right after the
//    barrier (latency hides under batch-0 compute)                 [R16 +1.5us]
//  - nontemporal stores keep x L3-resident across replays          [R16]
//  - xor8 on VALU (row_ror:8); xor4 stays ds_swizzle               [R18]
//  - 2-row fenced batches, static indexing, natural VGPR (~110)
// ---------------------------------------------------------------------------
__global__ __launch_bounds__(256) void bf_main(
    const float* __restrict__ x,
    const float* __restrict__ ang,
    float* __restrict__ out)
{
    __shared__ __align__(16) float cosT[TABN];
    __shared__ __align__(16) float sinT[TABN];
    const int tid  = threadIdx.x;
    const int lane = tid & 63;
    const int gwid = blockIdx.x * 4 + (tid >> 6);   // global wave id, 4 rows each

    const float4* xp = (const float4*)x   + (size_t)gwid * 4 * (DIM / 4) + lane;
    float4*       op = (float4*)      out + (size_t)gwid * 4 * (DIM / 4) + lane;

    // ---- batch 0 payload loads FIRST (hidden under table generation) -----
    float4 v0[2][4];
    #pragma unroll
    for (int r = 0; r < 2; ++r)
        #pragma unroll
        for (int c = 0; c < 4; ++c)
            v0[r][c] = xp[r * 256 + c * 64];

    // ---- in-kernel table generation: HW v_sin/v_cos (revolution input) ---
    {
        const float2* a2 = (const float2*)ang;
        const float r2pi = 0.15915494309189535f;   // 1/(2*pi)
        #pragma unroll 1
        for (int k = 0; k < TABN / 2 / 256; ++k) {   // 10 iterations
            const int idx = k * 256 + tid;           // pair index
            float2 a = a2[idx];
            float fa = a.x * r2pi; fa -= floorf(fa);
            float fb = a.y * r2pi; fb -= floorf(fb);
            float2 c, s;
            c.x = __builtin_amdgcn_cosf(fa);
            s.x = __builtin_amdgcn_sinf(fa);
            c.y = __builtin_amdgcn_cosf(fb);
            s.y = __builtin_amdgcn_sinf(fb);
            *(float2*)&cosT[2 * idx] = c;
            *(float2*)&sinT[2 * idx] = s;
        }
    }

    __syncthreads();

    // ---- batch 1 loads issue NOW: latency hides under batch-0 compute ----
    float4 v1[2][4];
    #pragma unroll
    for (int r = 0; r < 2; ++r)
        #pragma unroll
        for (int c = 0; c < 4; ++c)
            v1[r][c] = xp[(2 + r) * 256 + c * 64];

    {
        float4 (&v)[2][4] = v0;   // alias so XSTAGE sees `v`
        processBatch(v, cosT, sinT, lane);
    }
    #pragma unroll
    for (int r = 0; r < 2; ++r)
        #pragma unroll
        for (int c = 0; c < 4; ++c)
            storeRowNT(op + r * 256 + c * 64, v0[r][c]);

    asm volatile("" ::: "memory");   // fence: no cross-batch hoist/CSE

    {
        float4 (&v)[2][4] = v1;
        processBatch(v, cosT, sinT, lane);
    }
    #pragma unroll
    for (int r = 0; r < 2; ++r)
        #pragma unroll
        for (int c = 0; c < 4; ++c)
            storeRowNT(op + (2 + r) * 256 + c * 64, v1[r][c]);
}

extern "C" void kernel_launch(void* const* d_in, const int* in_sizes, int n_in,
                              void* d_out, int out_size, void* d_ws, size_t ws_size,
                              hipStream_t stream) {
    const float* x   = (const float*)d_in[0];
    const float* ang = (const float*)d_in[1];
    float* out = (float*)d_out;

    const int nrows = out_size / DIM;          // 16384
    // 4 waves/block x 4 rows/wave = 16 rows/block -> 1024 blocks,
    // 4 blocks/CU at 40KB LDS -> whole grid resident in one round.
    const int nblocks = nrows / 16;

    bf_main<<<nblocks, 256, 0, stream>>>(x, ang, out);
}